// Round 11
// baseline (1213.870 us; speedup 1.0000x reference)
//
#include <hip/hip_runtime.h>
#include <hip/hip_fp16.h>

#define N_IN_SZ   400000
#define N_OUT_SZ  200000
#define K_OFF     27
#define R_RULES   200000
#define NC        32
#define TOTAL_E   (K_OFF * R_RULES)     // 5,400,000

// chunk = o >> 6 (64 outputs); buckets chunk-major: b = chunk*27 + k
#define CH_SHIFT  6
#define CH_ROWS   64
#define NCHUNK    3125                   // 200000/64 exactly
#define NB        (NCHUNK * K_OFF)       // 84,375
#define NB_PAD    84992                  // 83*1024
#define N_CNT4    (NB_PAD / 4)           // 21,248
#define NSCANBLK  83

#define HIST_BLK  8
#define RPH       25000

typedef unsigned int u32;
typedef unsigned long long u64;
typedef __attribute__((ext_vector_type(8))) short bf16x8;
typedef __attribute__((ext_vector_type(4))) float f32x4;

// ---------------- ws layout (identical to R9/R10 — proven to fit) ------------
#define SORT_OFF    0ull
#define A_OFF       21600000ull
#define BSUM_OFF    (A_OFF + (u64)NB_PAD * 4)
#define BOFF_OFF    (BSUM_OFF + 1024ull)
#define WS_NEW_NEEDED (BOFF_OFF + 1024ull)         // 21,942,016

#define ACC_WORDS  (N_OUT_SZ * 16)
#define WS_F16_NEEDED  ((size_t)ACC_WORDS * 4)

__device__ __forceinline__ u32 pack_bf16(float lo, float hi) {
    return (__float_as_uint(hi) & 0xFFFF0000u) | (__float_as_uint(lo) >> 16);
}

// ===========================================================================
// sort pipeline (verbatim R9). entry = (o&63)<<24 | k<<19 | irow
// ===========================================================================
__global__ __launch_bounds__(256) void zero_cnt_kernel(uint4* __restrict__ A4)
{
    int i = blockIdx.x * 256 + threadIdx.x;
    if (i < N_CNT4) A4[i] = make_uint4(0, 0, 0, 0);
}

__global__ __launch_bounds__(256) void hist_kernel(
    const int* __restrict__ out_idx, u32* __restrict__ A)
{
    __shared__ u32 lh[NCHUNK];
    for (int t = threadIdx.x; t < NCHUNK; t += 256) lh[t] = 0;
    __syncthreads();
    const int k    = blockIdx.y;
    const int base = blockIdx.x * RPH;
    for (int r = base + threadIdx.x; r < base + RPH; r += 256)
        atomicAdd(&lh[((u32)out_idx[(size_t)k * R_RULES + r]) >> CH_SHIFT], 1u);
    __syncthreads();
    for (int t = threadIdx.x; t < NCHUNK; t += 256) {
        u32 v = lh[t];
        if (v) atomicAdd(&A[(u32)t * K_OFF + (u32)k], v);
    }
}

__global__ __launch_bounds__(256) void blocksum_kernel(
    const uint4* __restrict__ A4, u32* __restrict__ bsum)
{
    int i4 = blockIdx.x * 256 + threadIdx.x;
    uint4 c = A4[i4];
    u32 s = c.x + c.y + c.z + c.w;
    int lane = threadIdx.x & 63;
#pragma unroll
    for (int off = 32; off > 0; off >>= 1)
        s += __shfl_down(s, off);
    __shared__ u32 ws[4];
    int wid = threadIdx.x >> 6;
    if (lane == 0) ws[wid] = s;
    __syncthreads();
    if (threadIdx.x == 0)
        bsum[blockIdx.x] = ws[0] + ws[1] + ws[2] + ws[3];
}

__global__ __launch_bounds__(256) void scanblk_kernel(
    const u32* __restrict__ bsum, u32* __restrict__ boff)
{
    __shared__ u32 lds[NSCANBLK];
    int t = threadIdx.x;
    if (t < NSCANBLK) lds[t] = bsum[t];
    __syncthreads();
    if (t == 0) {
        u32 run = 0;
        for (int i = 0; i < NSCANBLK; ++i) { u32 v = lds[i]; lds[i] = run; run += v; }
    }
    __syncthreads();
    if (t < NSCANBLK) boff[t] = lds[t];
}

__global__ __launch_bounds__(256) void scanwrite_kernel(
    uint4* __restrict__ A4, const u32* __restrict__ boff)
{
    int i4 = blockIdx.x * 256 + threadIdx.x;
    uint4 c = A4[i4];
    u32 lsum = c.x + c.y + c.z + c.w;
    u32 s = lsum;
    int lane = threadIdx.x & 63;
#pragma unroll
    for (int off = 1; off < 64; off <<= 1) {
        u32 v = __shfl_up(s, off);
        if (lane >= off) s += v;
    }
    __shared__ u32 wsum[4], wbase[4];
    int wid = threadIdx.x >> 6;
    if (lane == 63) wsum[wid] = s;
    __syncthreads();
    if (threadIdx.x == 0) {
        u32 run = 0;
        for (int w = 0; w < 4; ++w) { wbase[w] = run; run += wsum[w]; }
    }
    __syncthreads();
    u32 base = boff[blockIdx.x] + wbase[wid] + (s - lsum);
    uint4 st;
    st.x = base;
    st.y = st.x + c.x;
    st.z = st.y + c.y;
    st.w = st.z + c.z;
    A4[i4] = st;
}

__global__ __launch_bounds__(256) void fill_kernel(
    const int* __restrict__ in_idx, const int* __restrict__ out_idx,
    u32* __restrict__ A, u32* __restrict__ sorted)
{
    __shared__ u32 lh[NCHUNK];
    __shared__ u32 lbase[NCHUNK];
    const int k    = blockIdx.y;
    const int base = blockIdx.x * RPH;

    for (int t = threadIdx.x; t < NCHUNK; t += 256) lh[t] = 0;
    __syncthreads();
    for (int r = base + threadIdx.x; r < base + RPH; r += 256)
        atomicAdd(&lh[((u32)out_idx[(size_t)k * R_RULES + r]) >> CH_SHIFT], 1u);
    __syncthreads();
    for (int t = threadIdx.x; t < NCHUNK; t += 256) {
        u32 v = lh[t];
        if (v) lbase[t] = atomicAdd(&A[(u32)t * K_OFF + (u32)k], v);
    }
    __syncthreads();
    for (int t = threadIdx.x; t < NCHUNK; t += 256) lh[t] = 0;
    __syncthreads();
    for (int r = base + threadIdx.x; r < base + RPH; r += 256) {
        u32 o  = (u32)out_idx[(size_t)k * R_RULES + r];
        u32 iv = (u32)in_idx[(size_t)k * R_RULES + r];
        u32 ch = o >> CH_SHIFT;
        u32 off = atomicAdd(&lh[ch], 1u);
        sorted[lbase[ch] + off] =
            ((o & (u32)(CH_ROWS - 1)) << 24) | ((u32)k << 19) | iv;
    }
}

// ===========================================================================
// gather (MFMA, bucket-staged): block = 64-row chunk, wave owns k = wave mod 4.
// Per 64-entry super-tile: ONE wave-wide load stages all entry words in regs;
// all 4 tiles' feat loads (8x dwordx4, independent) issue back-to-back, then
// 8 MFMAs drain. MLP per wave ~8 vmem instrs (vs 2 in R10). C scatters via
// ds_add_f32 into 65x33 LDS acc. Zero global atomics.
// ===========================================================================
#define TILE_LOAD(T, Q0, Q1) { \
    const u32 _em = (u32)__shfl((int)ew, (T) * 16 + r16); \
    const float4* _p = reinterpret_cast<const float4*>( \
        feat + (size_t)(_em & 0x7FFFFu) * NC) + quad * 2; \
    Q0 = _p[0]; Q1 = _p[1]; }

#define TILE_COMPUTE(T, Q0, Q1) { \
    union { u32 w[4]; bf16x8 v; } _au; \
    _au.w[0] = pack_bf16(Q0.x, Q0.y); \
    _au.w[1] = pack_bf16(Q0.z, Q0.w); \
    _au.w[2] = pack_bf16(Q1.x, Q1.y); \
    _au.w[3] = pack_bf16(Q1.z, Q1.w); \
    f32x4 _c0 = {0.f, 0.f, 0.f, 0.f}; \
    f32x4 _c1 = {0.f, 0.f, 0.f, 0.f}; \
    _c0 = __builtin_amdgcn_mfma_f32_16x16x32_bf16(_au.v, bl.v, _c0, 0, 0, 0); \
    _c1 = __builtin_amdgcn_mfma_f32_16x16x32_bf16(_au.v, bh.v, _c1, 0, 0, 0); \
    _Pragma("unroll") \
    for (int _rg = 0; _rg < 4; ++_rg) { \
        const u32 _ec = (u32)__shfl((int)ew, (T) * 16 + quad * 4 + _rg); \
        const int _ol = (int)(_ec >> 24); \
        atomicAdd(&acc[_ol * 33 + r16],      _c0[_rg]); \
        atomicAdd(&acc[_ol * 33 + 16 + r16], _c1[_rg]); \
    } }

__global__ __launch_bounds__(256, 4) void gather_mfma_kernel(
    const float* __restrict__ feat,    // [N_IN, 32]
    const float* __restrict__ weight,  // [27*32, 32]
    const u32*   __restrict__ sorted,  // [TOTAL_E]
    const u32*   __restrict__ A,       // post-fill: A[b] = end_b
    const float* __restrict__ bias,
    float*       __restrict__ out)     // [N_OUT, 32]
{
    __shared__ float acc[65 * 33];     // 8580 B; row 64 = trash for tails
    for (int t = threadIdx.x; t < 65 * 33; t += 256) acc[t] = 0.0f;
    __syncthreads();

    const int chunk = blockIdx.x;
    const int wave  = threadIdx.x >> 6;
    const int lane  = threadIdx.x & 63;
    const int r16   = lane & 15;       // entry-in-tile (A) / channel (C)
    const int quad  = lane >> 4;       // k-octet selector

    for (int k = wave; k < K_OFF; k += 4) {
        const u32 b  = (u32)chunk * K_OFF + (u32)k;
        const u32 bs = (b > 0) ? A[b - 1] : 0u;
        const u32 be = A[b];
        if (be <= bs) continue;

        // B fragments for W[k] (verbatim R10)
        union { u32 w[4]; bf16x8 v; } bl, bh;
        const float* wk = weight + (size_t)k * NC * NC;
#pragma unroll
        for (int ee = 0; ee < 4; ++ee) {
            const int kk0 = quad * 8 + 2 * ee;
            bl.w[ee] = pack_bf16(wk[(size_t)kk0 * NC + r16],
                                 wk[(size_t)(kk0 + 1) * NC + r16]);
            bh.w[ee] = pack_bf16(wk[(size_t)kk0 * NC + 16 + r16],
                                 wk[(size_t)(kk0 + 1) * NC + 16 + r16]);
        }

        for (u32 tb = bs; tb < be; tb += 64) {
            const u32 rem = be - tb;                 // >0
            // ---- stage up to 64 entry words: ONE coalesced load ----
            u32 ew = 0x40000000u;                    // ol=64 trash, k=0, irow=0
            if ((u32)lane < rem) ew = sorted[tb + (u32)lane];
            const int ntile = (int)((rem < 64u ? rem : 64u) + 15u) >> 4;

            float4 q00, q01, q10, q11, q20, q21, q30, q31;
            // ---- issue ALL feat loads (independent) ----
            TILE_LOAD(0, q00, q01);
            if (ntile > 1) TILE_LOAD(1, q10, q11);
            if (ntile > 2) TILE_LOAD(2, q20, q21);
            if (ntile > 3) TILE_LOAD(3, q30, q31);

            // ---- drain with MFMA + LDS scatter ----
            TILE_COMPUTE(0, q00, q01);
            if (ntile > 1) TILE_COMPUTE(1, q10, q11);
            if (ntile > 2) TILE_COMPUTE(2, q20, q21);
            if (ntile > 3) TILE_COMPUTE(3, q30, q31);
        }
    }
    __syncthreads();

    const int obase = chunk << CH_SHIFT;             // 3125*64 = 200000 exact
    for (int t = threadIdx.x; t < CH_ROWS * NC; t += 256) {
        const int o = t >> 5, c = t & 31;
        out[(size_t)(obase + o) * NC + c] = acc[o * 33 + c] + bias[c];
    }
}

// ===========================================================================
// Fallback paths (R4 pk-f16 atomics; R2 f32 atomics)
// ===========================================================================
__global__ __launch_bounds__(256) void zero_ws_kernel(uint4* __restrict__ ws)
{
    const int total = ACC_WORDS / 4;
    int idx = blockIdx.x * 256 + threadIdx.x;
    if (idx < total) ws[idx] = make_uint4(0, 0, 0, 0);
}

__global__ __launch_bounds__(256) void conv_scatter_f16_kernel(
    const float* __restrict__ feat, const float* __restrict__ weight,
    const int* __restrict__ in_idx, const int* __restrict__ out_idx,
    __half2* __restrict__ acc)
{
    __shared__ float2 Wlds[NC * 16];
    const int k = blockIdx.y;
    const float2* wg = reinterpret_cast<const float2*>(weight + k * NC * NC);
    for (int t = threadIdx.x; t < NC * 16; t += 256)
        Wlds[t] = wg[t];
    __syncthreads();
    const int j = threadIdx.x & 15;
    const int g = threadIdx.x >> 4;
    float2 wcol[NC];
#pragma unroll
    for (int i = 0; i < NC; ++i) wcol[i] = Wlds[i * 16 + j];
    const int rbase = blockIdx.x * 64;
    for (int rr = g; rr < 64; rr += 16) {
        const int r = rbase + rr;
        const int irow = in_idx[(size_t)k * R_RULES + r];
        const int orow = out_idx[(size_t)k * R_RULES + r];
        const float4* fv = reinterpret_cast<const float4*>(feat + (size_t)irow * NC);
        float a0 = 0.0f, a1 = 0.0f;
#pragma unroll
        for (int i0 = 0; i0 < 8; ++i0) {
            const float4 f = fv[i0];
            a0 += f.x * wcol[i0*4+0].x;  a1 += f.x * wcol[i0*4+0].y;
            a0 += f.y * wcol[i0*4+1].x;  a1 += f.y * wcol[i0*4+1].y;
            a0 += f.z * wcol[i0*4+2].x;  a1 += f.z * wcol[i0*4+2].y;
            a0 += f.w * wcol[i0*4+3].x;  a1 += f.w * wcol[i0*4+3].y;
        }
        unsafeAtomicAdd(acc + (size_t)orow * 16 + j, __floats2half2_rn(a0, a1));
    }
}

__global__ __launch_bounds__(256) void unpack_kernel(
    const __half2* __restrict__ acc, const float* __restrict__ bias,
    float* __restrict__ out)
{
    int t = blockIdx.x * 256 + threadIdx.x;
    if (t >= ACC_WORDS) return;
    const int j = t & 15;
    const float2 v = __half22float2(acc[t]);
    const float2 b = reinterpret_cast<const float2*>(bias)[j];
    float2 o; o.x = v.x + b.x; o.y = v.y + b.y;
    reinterpret_cast<float2*>(out)[t] = o;
}

__global__ __launch_bounds__(256) void init_out_kernel(
    const float* __restrict__ bias, float* __restrict__ out)
{
    int idx = blockIdx.x * 256 + threadIdx.x;
    const int total4 = N_OUT_SZ * NC / 4;
    if (idx >= total4) return;
    int c0 = (idx * 4) & (NC - 1);
    float4 b;
    b.x = bias[c0+0]; b.y = bias[c0+1]; b.z = bias[c0+2]; b.w = bias[c0+3];
    reinterpret_cast<float4*>(out)[idx] = b;
}

__global__ __launch_bounds__(256) void conv_scatter_kernel(
    const float* __restrict__ feat, const float* __restrict__ weight,
    const int* __restrict__ in_idx, const int* __restrict__ out_idx,
    float* __restrict__ out)
{
    __shared__ float Wlds[NC * NC];
    const int k  = blockIdx.y;
    const int c  = threadIdx.x & (NC - 1);
    const int rg = threadIdx.x >> 5;
    for (int t = threadIdx.x; t < NC * NC; t += 256)
        Wlds[t] = weight[k * NC * NC + t];
    __syncthreads();
    float wcol[NC];
#pragma unroll
    for (int i = 0; i < NC; ++i) wcol[i] = Wlds[i * NC + c];
    const int rbase = blockIdx.x * 64;
    for (int rr = rg; rr < 64; rr += 8) {
        const int r = rbase + rr;
        const int irow = in_idx[(size_t)k * R_RULES + r];
        const int orow = out_idx[(size_t)k * R_RULES + r];
        const float4* fv = reinterpret_cast<const float4*>(feat + (size_t)irow * NC);
        float acc = 0.0f;
#pragma unroll
        for (int i0 = 0; i0 < 8; ++i0) {
            const float4 f = fv[i0];
            acc += f.x * wcol[i0*4+0];
            acc += f.y * wcol[i0*4+1];
            acc += f.z * wcol[i0*4+2];
            acc += f.w * wcol[i0*4+3];
        }
        atomicAdd(out + (size_t)orow * NC + c, acc);
    }
}

// ---------------------------------------------------------------------------
extern "C" void kernel_launch(void* const* d_in, const int* in_sizes, int n_in,
                              void* d_out, int out_size, void* d_ws, size_t ws_size,
                              hipStream_t stream)
{
    const float* feat    = (const float*)d_in[0];
    const float* weight  = (const float*)d_in[1];
    const float* bias    = (const float*)d_in[2];
    const int*   in_idx  = (const int*)d_in[3];
    const int*   out_idx = (const int*)d_in[4];
    float*       out     = (float*)d_out;

    if (ws_size >= WS_NEW_NEEDED) {
        char* ws = (char*)d_ws;
        u32* sorted = (u32*)(ws + SORT_OFF);
        u32* A      = (u32*)(ws + A_OFF);
        u32* bsum   = (u32*)(ws + BSUM_OFF);
        u32* boff   = (u32*)(ws + BOFF_OFF);

        zero_cnt_kernel<<<NSCANBLK, 256, 0, stream>>>((uint4*)A);
        {
            dim3 grid(HIST_BLK, K_OFF);
            hist_kernel<<<grid, 256, 0, stream>>>(out_idx, A);
        }
        blocksum_kernel<<<NSCANBLK, 256, 0, stream>>>((const uint4*)A, bsum);
        scanblk_kernel<<<1, 256, 0, stream>>>(bsum, boff);
        scanwrite_kernel<<<NSCANBLK, 256, 0, stream>>>((uint4*)A, boff);
        {
            dim3 grid(HIST_BLK, K_OFF);
            fill_kernel<<<grid, 256, 0, stream>>>(in_idx, out_idx, A, sorted);
        }
        gather_mfma_kernel<<<NCHUNK, 256, 0, stream>>>(feat, weight, sorted, A, bias, out);
    } else if (ws_size >= WS_F16_NEEDED) {
        __half2* acc = (__half2*)d_ws;
        zero_ws_kernel<<<(ACC_WORDS / 4 + 255) / 256, 256, 0, stream>>>((uint4*)d_ws);
        dim3 grid(R_RULES / 64, K_OFF);
        conv_scatter_f16_kernel<<<grid, 256, 0, stream>>>(feat, weight, in_idx, out_idx, acc);
        unpack_kernel<<<ACC_WORDS / 256, 256, 0, stream>>>(acc, bias, out);
    } else {
        int total4 = N_OUT_SZ * NC / 4;
        init_out_kernel<<<(total4 + 255) / 256, 256, 0, stream>>>(bias, out);
        dim3 grid(R_RULES / 64, K_OFF);
        conv_scatter_kernel<<<grid, 256, 0, stream>>>(feat, weight, in_idx, out_idx, out);
    }
}

// Round 12
// 308.024 us; speedup vs baseline: 3.9408x; 3.9408x over previous
//
#include <hip/hip_runtime.h>
#include <hip/hip_fp16.h>

#define N_IN_SZ   400000
#define N_OUT_SZ  200000
#define K_OFF     27
#define R_RULES   200000
#define NC        32

typedef unsigned int u32;
typedef __fp16 half2_t __attribute__((ext_vector_type(2)));

// ---------------- ws layouts ----------------
// Path A: f16 feat table (400000*32*2 = 25.6 MB) + f16 accumulator (12.8 MB)
#define TAB_OFF      0ull
#define ACC_A_OFF    25600000ull
#define WS_A_NEEDED  (ACC_A_OFF + 12800000ull)     // 38,400,000
// Path B (R4): f16 accumulator at offset 0
#define ACC_WORDS    (N_OUT_SZ * 16)               // 3.2M half2
#define WS_B_NEEDED  ((size_t)ACC_WORDS * 4)       // 12.8 MB

__device__ __forceinline__ half2_t bc_h2(u32 w) {
    union { u32 u; half2_t v; } x; x.u = w; return x.v;
}

// ===========================================================================
// zero f16 accumulators (800K uint4)
// ===========================================================================
__global__ __launch_bounds__(256) void zero_acc_kernel(uint4* __restrict__ ws)
{
    const int total = ACC_WORDS / 4;
    int idx = blockIdx.x * 256 + threadIdx.x;
    if (idx < total) ws[idx] = make_uint4(0, 0, 0, 0);
}

// ===========================================================================
// feat f32 -> f16 table (rows become 64 B = ONE cache line per gather)
// ===========================================================================
__global__ __launch_bounds__(256) void convert_kernel(
    const float4* __restrict__ feat4, uint4* __restrict__ tab4)
{
    int t = blockIdx.x * 256 + threadIdx.x;        // 0 .. 1.6M
    if (t >= (N_IN_SZ * NC / 8)) return;
    float4 f0 = feat4[2 * t];
    float4 f1 = feat4[2 * t + 1];
    union { __half2 h; u32 u; } a, b, c, d;
    a.h = __floats2half2_rn(f0.x, f0.y);
    b.h = __floats2half2_rn(f0.z, f0.w);
    c.h = __floats2half2_rn(f1.x, f1.y);
    d.h = __floats2half2_rn(f1.z, f1.w);
    tab4[t] = make_uint4(a.u, b.u, c.u, d.u);
}

// ===========================================================================
// Path A conv: 16-lane group per rule; lane j = channels (2j, 2j+1).
// Feat row = 4 uint4 broadcast loads (64 B, 1 line). Weights as packed half2
// pairs hoisted to 32 VGPRs (k uniform per block). v_dot2 f16 math.
// 2-rule ping-pong. pk-f16 atomic scatter (proven R4 path).
// ===========================================================================
#define LOADT(X0, X1, X2, X3, IR) { \
    const uint4* _p = reinterpret_cast<const uint4*>(tab + (size_t)(IR) * 16); \
    X0 = _p[0]; X1 = _p[1]; X2 = _p[2]; X3 = _p[3]; }

#if __has_builtin(__builtin_amdgcn_fdot2)
#define DOT2(ACC, FP, WP) ACC = __builtin_amdgcn_fdot2(bc_h2(FP), bc_h2(WP), ACC, false);
#else
#define DOT2(ACC, FP, WP) { \
    float2 _f = __half22float2(*(const __half2*)&(FP)); \
    float2 _w = __half22float2(*(const __half2*)&(WP)); \
    ACC += _f.x * _w.x + _f.y * _w.y; }
#endif

#define COMPQ(X, Q) { \
    DOT2(a0, X.x, w0[(Q)*4+0]); DOT2(a1, X.x, w1[(Q)*4+0]); \
    DOT2(a0, X.y, w0[(Q)*4+1]); DOT2(a1, X.y, w1[(Q)*4+1]); \
    DOT2(a0, X.z, w0[(Q)*4+2]); DOT2(a1, X.z, w1[(Q)*4+2]); \
    DOT2(a0, X.w, w0[(Q)*4+3]); DOT2(a1, X.w, w1[(Q)*4+3]); }

#define COMP(X0, X1, X2, X3, OD) { \
    float a0 = 0.f, a1 = 0.f; \
    COMPQ(X0, 0); COMPQ(X1, 1); COMPQ(X2, 2); COMPQ(X3, 3); \
    unsafeAtomicAdd(acc + (size_t)(OD) * 16 + j, __floats2half2_rn(a0, a1)); }

__global__ __launch_bounds__(256) void conv_a_kernel(
    const u32*   __restrict__ tab,      // [N_IN, 16] f16-pair dwords
    const float* __restrict__ weight,   // [27*32, 32] f32
    const int*   __restrict__ in_idx,   // [27, R]
    const int*   __restrict__ out_idx,  // [27, R]
    __half2*     __restrict__ acc)      // [N_OUT, 16]
{
    __shared__ u32 Wp[16 * 32];         // Wp[i2*32+c] = half2(w[2i2][c], w[2i2+1][c])
    const int k = blockIdx.y;
    for (int t = threadIdx.x; t < 512; t += 256) {
        const int i2 = t >> 5, c = t & 31;
        union { __half2 h; u32 u; } x;
        x.h = __floats2half2_rn(weight[(size_t)k * 1024 + (2 * i2) * 32 + c],
                                weight[(size_t)k * 1024 + (2 * i2 + 1) * 32 + c]);
        Wp[t] = x.u;
    }
    __syncthreads();

    const int j = threadIdx.x & 15;     // channel pair (2j, 2j+1)
    const int g = threadIdx.x >> 4;     // rule group 0..15

    u32 w0[16], w1[16];                 // 32 VGPRs, truly resident (k uniform)
#pragma unroll
    for (int i2 = 0; i2 < 16; ++i2) {
        w0[i2] = Wp[i2 * 32 + 2 * j];
        w1[i2] = Wp[i2 * 32 + 2 * j + 1];
    }

    const size_t base = (size_t)k * R_RULES + blockIdx.x * 64 + g;
    const int ir0 = in_idx[base],      ir1 = in_idx[base + 16];
    const int ir2 = in_idx[base + 32], ir3 = in_idx[base + 48];
    const int od0 = out_idx[base],      od1 = out_idx[base + 16];
    const int od2 = out_idx[base + 32], od3 = out_idx[base + 48];

    uint4 A0, A1, A2, A3, B0, B1, B2, B3;
    LOADT(A0, A1, A2, A3, ir0);
    LOADT(B0, B1, B2, B3, ir1);
    COMP(A0, A1, A2, A3, od0);
    LOADT(A0, A1, A2, A3, ir2);
    COMP(B0, B1, B2, B3, od1);
    LOADT(B0, B1, B2, B3, ir3);
    COMP(A0, A1, A2, A3, od2);
    COMP(B0, B1, B2, B3, od3);
}

// ===========================================================================
// unpack: out[o][2j..2j+1] = float(acc) + bias
// ===========================================================================
__global__ __launch_bounds__(256) void unpack_kernel(
    const __half2* __restrict__ acc, const float* __restrict__ bias,
    float* __restrict__ out)
{
    int t = blockIdx.x * 256 + threadIdx.x;
    if (t >= ACC_WORDS) return;
    const int j = t & 15;
    const float2 v = __half22float2(acc[t]);
    const float2 b = reinterpret_cast<const float2*>(bias)[j];
    float2 o; o.x = v.x + b.x; o.y = v.y + b.y;
    reinterpret_cast<float2*>(out)[t] = o;
}

// ===========================================================================
// Path B: verbatim R4 (proven 634 µs)
// ===========================================================================
__global__ __launch_bounds__(256) void conv_scatter_f16_kernel(
    const float* __restrict__ feat, const float* __restrict__ weight,
    const int* __restrict__ in_idx, const int* __restrict__ out_idx,
    __half2* __restrict__ acc)
{
    __shared__ float2 Wlds[NC * 16];
    const int k = blockIdx.y;
    const float2* wg = reinterpret_cast<const float2*>(weight + k * NC * NC);
    for (int t = threadIdx.x; t < NC * 16; t += 256)
        Wlds[t] = wg[t];
    __syncthreads();
    const int j = threadIdx.x & 15;
    const int g = threadIdx.x >> 4;
    float2 wcol[NC];
#pragma unroll
    for (int i = 0; i < NC; ++i) wcol[i] = Wlds[i * 16 + j];
    const int rbase = blockIdx.x * 64;
    for (int rr = g; rr < 64; rr += 16) {
        const int r = rbase + rr;
        const int irow = in_idx[(size_t)k * R_RULES + r];
        const int orow = out_idx[(size_t)k * R_RULES + r];
        const float4* fv = reinterpret_cast<const float4*>(feat + (size_t)irow * NC);
        float a0 = 0.0f, a1 = 0.0f;
#pragma unroll
        for (int i0 = 0; i0 < 8; ++i0) {
            const float4 f = fv[i0];
            a0 += f.x * wcol[i0*4+0].x;  a1 += f.x * wcol[i0*4+0].y;
            a0 += f.y * wcol[i0*4+1].x;  a1 += f.y * wcol[i0*4+1].y;
            a0 += f.z * wcol[i0*4+2].x;  a1 += f.z * wcol[i0*4+2].y;
            a0 += f.w * wcol[i0*4+3].x;  a1 += f.w * wcol[i0*4+3].y;
        }
        unsafeAtomicAdd(acc + (size_t)orow * 16 + j, __floats2half2_rn(a0, a1));
    }
}

// Path C fallback: R2 f32 atomics (no ws)
__global__ __launch_bounds__(256) void init_out_kernel(
    const float* __restrict__ bias, float* __restrict__ out)
{
    int idx = blockIdx.x * 256 + threadIdx.x;
    const int total4 = N_OUT_SZ * NC / 4;
    if (idx >= total4) return;
    int c0 = (idx * 4) & (NC - 1);
    float4 b;
    b.x = bias[c0+0]; b.y = bias[c0+1]; b.z = bias[c0+2]; b.w = bias[c0+3];
    reinterpret_cast<float4*>(out)[idx] = b;
}

__global__ __launch_bounds__(256) void conv_scatter_kernel(
    const float* __restrict__ feat, const float* __restrict__ weight,
    const int* __restrict__ in_idx, const int* __restrict__ out_idx,
    float* __restrict__ out)
{
    __shared__ float Wlds[NC * NC];
    const int k  = blockIdx.y;
    const int c  = threadIdx.x & (NC - 1);
    const int rg = threadIdx.x >> 5;
    for (int t = threadIdx.x; t < NC * NC; t += 256)
        Wlds[t] = weight[k * NC * NC + t];
    __syncthreads();
    float wcol[NC];
#pragma unroll
    for (int i = 0; i < NC; ++i) wcol[i] = Wlds[i * NC + c];
    const int rbase = blockIdx.x * 64;
    for (int rr = rg; rr < 64; rr += 8) {
        const int r = rbase + rr;
        const int irow = in_idx[(size_t)k * R_RULES + r];
        const int orow = out_idx[(size_t)k * R_RULES + r];
        const float4* fv = reinterpret_cast<const float4*>(feat + (size_t)irow * NC);
        float acc = 0.0f;
#pragma unroll
        for (int i0 = 0; i0 < 8; ++i0) {
            const float4 f = fv[i0];
            acc += f.x * wcol[i0*4+0];
            acc += f.y * wcol[i0*4+1];
            acc += f.z * wcol[i0*4+2];
            acc += f.w * wcol[i0*4+3];
        }
        atomicAdd(out + (size_t)orow * NC + c, acc);
    }
}

// ---------------------------------------------------------------------------
extern "C" void kernel_launch(void* const* d_in, const int* in_sizes, int n_in,
                              void* d_out, int out_size, void* d_ws, size_t ws_size,
                              hipStream_t stream)
{
    const float* feat    = (const float*)d_in[0];
    const float* weight  = (const float*)d_in[1];
    const float* bias    = (const float*)d_in[2];
    const int*   in_idx  = (const int*)d_in[3];
    const int*   out_idx = (const int*)d_in[4];
    float*       out     = (float*)d_out;

    if (ws_size >= WS_A_NEEDED) {
        u32*     tab = (u32*)((char*)d_ws + TAB_OFF);
        __half2* acc = (__half2*)((char*)d_ws + ACC_A_OFF);

        zero_acc_kernel<<<(ACC_WORDS / 4 + 255) / 256, 256, 0, stream>>>(
            (uint4*)((char*)d_ws + ACC_A_OFF));
        convert_kernel<<<(N_IN_SZ * NC / 8 + 255) / 256, 256, 0, stream>>>(
            (const float4*)feat, (uint4*)tab);
        {
            dim3 grid(R_RULES / 64, K_OFF);
            conv_a_kernel<<<grid, 256, 0, stream>>>(tab, weight, in_idx, out_idx, acc);
        }
        unpack_kernel<<<ACC_WORDS / 256, 256, 0, stream>>>(acc, bias, out);
    } else if (ws_size >= WS_B_NEEDED) {
        __half2* acc = (__half2*)d_ws;
        zero_acc_kernel<<<(ACC_WORDS / 4 + 255) / 256, 256, 0, stream>>>((uint4*)d_ws);
        dim3 grid(R_RULES / 64, K_OFF);
        conv_scatter_f16_kernel<<<grid, 256, 0, stream>>>(feat, weight, in_idx, out_idx, acc);
        unpack_kernel<<<ACC_WORDS / 256, 256, 0, stream>>>(acc, bias, out);
    } else {
        int total4 = N_OUT_SZ * NC / 4;
        init_out_kernel<<<(total4 + 255) / 256, 256, 0, stream>>>(bias, out);
        dim3 grid(R_RULES / 64, K_OFF);
        conv_scatter_kernel<<<grid, 256, 0, stream>>>(feat, weight, in_idx, out_idx, out);
    }
}